// Round 12
// baseline (368.956 us; speedup 1.0000x reference)
//
#include <hip/hip_runtime.h>

typedef short bhalf8 __attribute__((ext_vector_type(8)));   // 8 x bf16 = 4 VGPRs
typedef short short4v __attribute__((ext_vector_type(4)));  // 4 x bf16 = 2 VGPRs
typedef unsigned uint4v __attribute__((ext_vector_type(4)));
typedef float floatx4 __attribute__((ext_vector_type(4)));  // MFMA C/D frag

#define D_MODEL 1024
#define SEQ     2048
#define BATCH   2
#define NHEAD   16
#define DH      64

// global -> LDS direct DMA (m97: width 16 emits global_load_lds_dwordx4).
// LDS dest is WAVE-UNIFORM base; lane i lands at base + i*16 (no padding!).
#define GLDS(g, l) __builtin_amdgcn_global_load_lds( \
    (const __attribute__((address_space(1))) void*)(g), \
    (__attribute__((address_space(3))) void*)(l), 16, 0, 0)

static __device__ __forceinline__ short f2bf(float f) {
    unsigned u = __builtin_bit_cast(unsigned, f);
    u = (u + 0x7fffu + ((u >> 16) & 1u)) >> 16;   // RNE fp32 -> bf16
    return (short)u;
}
static __device__ __forceinline__ unsigned pack2(float a, float b) {
    return (unsigned)(unsigned short)f2bf(a) | ((unsigned)(unsigned short)f2bf(b) << 16);
}
// HW packed fp32->bf16 (RNE); no builtin on gfx950, inline asm per T12 recipe.
static __device__ __forceinline__ unsigned cvt_pk_bf16(float lo, float hi) {
    unsigned r;
    asm("v_cvt_pk_bf16_f32 %0, %1, %2" : "=v"(r) : "v"(lo), "v"(hi));
    return r;
}

// ---------------------------------------------------------------------------
// Merged cast kernel: bid<2048 -> x (fp32->bf16); else wq/wk/wv/wo into wall.
// ---------------------------------------------------------------------------
__global__ __launch_bounds__(256) void cast_all(const float* __restrict__ x,
                                                const float* __restrict__ wq,
                                                const float* __restrict__ wk,
                                                const float* __restrict__ wv,
                                                const float* __restrict__ wo,
                                                short* __restrict__ xb,
                                                short* __restrict__ wall) {
    const int bid = blockIdx.x;
    const float* s;
    short* d;
    int i;
    if (bid < 2048) {
        s = x; d = xb;
        i = (bid * 256 + threadIdx.x) * 8;
    } else {
        const int wb = bid - 2048;           // 0..2047
        const int which = wb >> 9;           // 0..3
        s = (which == 0) ? wq : (which == 1) ? wk : (which == 2) ? wv : wo;
        d = wall + (size_t)which * (D_MODEL * D_MODEL);
        i = ((wb & 511) * 256 + threadIdx.x) * 8;
    }
    float4 a = *(const float4*)(s + i);
    float4 b = *(const float4*)(s + i + 4);
    uint4 u = {pack2(a.x, a.y), pack2(a.z, a.w), pack2(b.x, b.y), pack2(b.z, b.w)};
    *(uint4*)(d + i) = u;
}

// ---------------------------------------------------------------------------
// Fused QKV GEMM v2 — 256x256 tile, BK=32, RING-OF-3 counted-vmcnt pipeline.
// (unchanged — dropped out of top-5)
// ---------------------------------------------------------------------------
#define MFMA_BF16 __builtin_amdgcn_mfma_f32_16x16x32_bf16

#define QISSUE(kt, s) do {                                                    \
    char* ab_ = pool + (s) * 16384 + (w * 32) * 64;                           \
    char* bb_ = pool + 49152 + (s) * 16384 + (w * 32) * 64;                   \
    GLDS(Ag + (size_t)(kt) * 32, ab_);                                        \
    GLDS(Ag + (size_t)(kt) * 32 + 16 * 1024, ab_ + 1024);                     \
    GLDS(Wg + (size_t)(kt) * 32, bb_);                                        \
    GLDS(Wg + (size_t)(kt) * 32 + 16 * 1024, bb_ + 1024);                     \
} while (0)

#define QCOMP(s) do {                                                         \
    const short(*As_)[32] = (const short(*)[32])(pool + (s) * 16384);         \
    const short(*Bs_)[32] = (const short(*)[32])(pool + 49152 + (s) * 16384); \
    bhalf8 af_[8], bf_[4];                                                    \
    _Pragma("unroll")                                                         \
    for (int m_ = 0; m_ < 8; ++m_)                                            \
        af_[m_] = *(const bhalf8*)&As_[wr * 128 + m_ * 16 + l16][quad * 8];   \
    _Pragma("unroll")                                                         \
    for (int n_ = 0; n_ < 4; ++n_)                                            \
        bf_[n_] = *(const bhalf8*)&Bs_[wc * 64 + n_ * 16 + l16][quad * 8];    \
    __builtin_amdgcn_s_setprio(1);                                            \
    _Pragma("unroll")                                                         \
    for (int m_ = 0; m_ < 8; ++m_)                                            \
        _Pragma("unroll")                                                     \
        for (int n_ = 0; n_ < 4; ++n_)                                        \
            acc[m_][n_] = MFMA_BF16(af_[m_], bf_[n_], acc[m_][n_], 0, 0, 0);  \
    __builtin_amdgcn_s_setprio(0);                                            \
} while (0)

__global__ __launch_bounds__(512) void gemm_qkv2(const short* __restrict__ A,
                                                 const short* __restrict__ W,
                                                 short* __restrict__ Qo,
                                                 short* __restrict__ Ko,
                                                 short* __restrict__ Vt) {
    __shared__ __align__(16) char pool[98304];   // ring 96 KB; epilogue aliases
    const int t    = threadIdx.x;
    const int w    = t >> 6, lane = t & 63, quad = lane >> 4, l16 = lane & 15;
    const int wr   = w >> 2, wc = w & 3;
    const int bm   = blockIdx.x * 256;
    const int by   = (int)blockIdx.y;
    const int bn   = by * 256;

    const short* Ag = A + (size_t)(bm + w * 32 + (lane >> 2)) * 1024 + (lane & 3) * 8;
    const short* Wg = W + (size_t)(bn + w * 32 + (lane >> 2)) * 1024 + (lane & 3) * 8;

    floatx4 acc[8][4];
#pragma unroll
    for (int m = 0; m < 8; ++m)
#pragma unroll
        for (int n = 0; n < 4; ++n) {
            floatx4 z = {0.f, 0.f, 0.f, 0.f};
            acc[m][n] = z;
        }

    QISSUE(0, 0);
    QISSUE(1, 1);
    int sc_ = 0, sn_ = 2;
#pragma unroll 1
    for (int kt = 0; kt < 30; ++kt) {
        asm volatile("s_waitcnt vmcnt(4)" ::: "memory");  // tile kt landed
        __builtin_amdgcn_s_barrier();
        QISSUE(kt + 2, sn_);
        QCOMP(sc_);
        sc_ = (sc_ == 2) ? 0 : sc_ + 1;
        sn_ = (sn_ == 2) ? 0 : sn_ + 1;
    }
    asm volatile("s_waitcnt vmcnt(4)" ::: "memory");
    __builtin_amdgcn_s_barrier();
    QCOMP(sc_);
    sc_ = (sc_ == 2) ? 0 : sc_ + 1;
    asm volatile("s_waitcnt vmcnt(0)" ::: "memory");
    __builtin_amdgcn_s_barrier();
    QCOMP(sc_);

    // ---- epilogue: 2 halves of 128 rows staged in dead ring LDS ----
    __syncthreads();
    short (*Ct)[268] = (short(*)[268])pool;               // 128x268x2 = 68608 B
    if (by < 8) {
        short* outp = (by < 4) ? Qo : Ko;
        const int colbase = (by < 4) ? bn : bn - 1024;
        for (int hh = 0; hh < 2; ++hh) {
            if (wr == hh) {
#pragma unroll
                for (int m = 0; m < 8; ++m)
#pragma unroll
                    for (int n = 0; n < 4; ++n)
#pragma unroll
                        for (int g = 0; g < 4; ++g)
                            Ct[m * 16 + quad * 4 + g][wc * 64 + n * 16 + l16] =
                                f2bf(acc[m][n][g]);
            }
            __syncthreads();
            {
                const int r = t >> 2, c0 = (t & 3) * 64;
#pragma unroll
                for (int p = 0; p < 8; ++p)
                    *(uint4*)(outp + (size_t)(bm + hh * 128 + r) * 1024 +
                              colbase + c0 + p * 8) =
                        *(const uint4*)&Ct[r][c0 + p * 8];
            }
            __syncthreads();
        }
    } else {
        const int nbase = bn - 2048;
        for (int hh = 0; hh < 2; ++hh) {
            if ((wc >> 1) == hh) {
#pragma unroll
                for (int m = 0; m < 8; ++m)
#pragma unroll
                    for (int n = 0; n < 4; ++n)
#pragma unroll
                        for (int g = 0; g < 4; ++g)
                            Ct[wc * 64 + n * 16 + l16 - hh * 128]
                              [wr * 128 + m * 16 + quad * 4 + g] =
                                f2bf(acc[m][n][g]);
            }
            __syncthreads();
            {
                const int r = t >> 2, c0 = (t & 3) * 64;
#pragma unroll
                for (int p = 0; p < 8; ++p)
                    *(uint4*)(Vt + (size_t)(nbase + hh * 128 + r) * 4096 +
                              bm + c0 + p * 8) =
                        *(const uint4*)&Ct[r][c0 + p * 8];
            }
            __syncthreads();
        }
    }
}

// ---------------------------------------------------------------------------
// O-projection GEMM v2 — ring-of-3 counted-vmcnt pipeline (same transform
// that took gemm_qkv 68 -> <40 us). 256 thr, tile 128x64, BK=32, 32 K-tiles.
// Ring: 3 slots x (A 8KB + B 4KB) = 36 KB; fp32 epilogue Ctf aliases pool.
// Per thread per K-tile: 3 GLDS (2 A + 1 B) -> steady-state vmcnt(3).
// ---------------------------------------------------------------------------
#define OISSUE(kt, s) do {                                                    \
    char* ab_ = pool + (s) * 12288 + w * 2048;                                \
    char* bb_ = pool + (s) * 12288 + 8192 + w * 1024;                         \
    GLDS(Ag + (size_t)(kt) * 32, ab_);                                        \
    GLDS(Ag + (size_t)(kt) * 32 + 16 * 1024, ab_ + 1024);                     \
    GLDS(Wg + (size_t)(kt) * 32, bb_);                                        \
} while (0)

#define OCOMP(s) do {                                                         \
    const short(*As_)[32] = (const short(*)[32])(pool + (s) * 12288);         \
    const short(*Bs_)[32] = (const short(*)[32])(pool + (s) * 12288 + 8192);  \
    bhalf8 af_[4], bf_[2];                                                    \
    _Pragma("unroll")                                                         \
    for (int m_ = 0; m_ < 4; ++m_)                                            \
        af_[m_] = *(const bhalf8*)&As_[qm + m_ * 16 + l16][quad * 8];         \
    _Pragma("unroll")                                                         \
    for (int n_ = 0; n_ < 2; ++n_)                                            \
        bf_[n_] = *(const bhalf8*)&Bs_[qn + n_ * 16 + l16][quad * 8];         \
    __builtin_amdgcn_s_setprio(1);                                            \
    _Pragma("unroll")                                                         \
    for (int m_ = 0; m_ < 4; ++m_)                                            \
        _Pragma("unroll")                                                     \
        for (int n_ = 0; n_ < 2; ++n_)                                        \
            acc[m_][n_] = MFMA_BF16(af_[m_], bf_[n_], acc[m_][n_], 0, 0, 0);  \
    __builtin_amdgcn_s_setprio(0);                                            \
} while (0)

__global__ __launch_bounds__(256) void gemm_o2(const short* __restrict__ A,
                                               const short* __restrict__ W,
                                               float* __restrict__ C) {
    __shared__ __align__(16) char pool[36864];   // ring 36 KB; Ctf aliases
    const int t    = threadIdx.x;
    const int w    = t >> 6, lane = t & 63, quad = lane >> 4, l16 = lane & 15;
    const int bm = blockIdx.x * 128, bn = blockIdx.y * 64;
    const int qm = (w >> 1) * 64, qn = (w & 1) * 32;

    const short* Ag = A + (size_t)(bm + w * 32 + (lane >> 2)) * 1024 + (lane & 3) * 8;
    const short* Wg = W + (size_t)(bn + w * 16 + (lane >> 2)) * 1024 + (lane & 3) * 8;

    floatx4 acc[4][2];
#pragma unroll
    for (int m = 0; m < 4; ++m)
#pragma unroll
        for (int n = 0; n < 2; ++n) {
            floatx4 z = {0.f, 0.f, 0.f, 0.f};
            acc[m][n] = z;
        }

    OISSUE(0, 0);
    OISSUE(1, 1);
    int sc_ = 0, sn_ = 2;
#pragma unroll 1
    for (int kt = 0; kt < 30; ++kt) {
        asm volatile("s_waitcnt vmcnt(3)" ::: "memory");  // tile kt landed
        __builtin_amdgcn_s_barrier();
        OISSUE(kt + 2, sn_);
        OCOMP(sc_);
        sc_ = (sc_ == 2) ? 0 : sc_ + 1;
        sn_ = (sn_ == 2) ? 0 : sn_ + 1;
    }
    asm volatile("s_waitcnt vmcnt(3)" ::: "memory");
    __builtin_amdgcn_s_barrier();
    OCOMP(sc_);
    sc_ = (sc_ == 2) ? 0 : sc_ + 1;
    asm volatile("s_waitcnt vmcnt(0)" ::: "memory");
    __builtin_amdgcn_s_barrier();
    OCOMP(sc_);

    // ---- fp32 LDS epilogue, line-complete stores (aliases ring) ----
    __syncthreads();
    float (*Ctf)[68] = (float(*)[68])pool;            // 128x68x4 = 34816 B
#pragma unroll
    for (int im = 0; im < 4; ++im)
#pragma unroll
        for (int jn = 0; jn < 2; ++jn)
#pragma unroll
            for (int g = 0; g < 4; ++g)
                Ctf[qm + im * 16 + quad * 4 + g][qn + jn * 16 + l16] = acc[im][jn][g];
    __syncthreads();
#pragma unroll
    for (int pass = 0; pass < 8; ++pass) {
        const int r = (t >> 4) + pass * 16;
        const int c = (t & 15) * 4;
        float4 u = *(const float4*)&Ctf[r][c];
        *(float4*)(C + (size_t)(bm + r) * 1024 + bn + c) = u;
    }
}

// ---------------------------------------------------------------------------
// Flash attention v18 — v17 body + 3 independent blocks/CU via split-k pairs.
// v13-v17 all ~320 TF; v17 showed ~27% issue-bound at only 2 barrier
// domains/CU. v17's footprint (44 VGPR, 36.9KB LDS) fits 3 blocks/CU.
// Grid 768: CU c hosts bids {c, 256+c, 512+c}, all same bh=c&31 (L2-local),
// same g=(c>>5): tiles {qt=15-g half0 (16-g chunks), qt=15-g half1 (16-g),
// qt=g whole (2g+2)} = 34 chunk-units/CU, max serial 16, three independent
// barrier domains. Fixed-CB softmax => k-half partials additive. Split
// tiles combine via split-K semaphore: both halves write fp32 partials to
// per-half slabs, __threadfence, atomicAdd ticket; second arrival combines
// + stores Y. No spinning (deadlock-free regardless of residency).
// Flags zeroed by hipMemsetAsync each launch; ws_size guarded (v17 fallback).
// ---------------------------------------------------------------------------
#define ATTN_BODY(KERN_NC, KERN_KBASE)                                        \
    uint4 kreg, vreg;                                                         \
    kreg = *(const uint4*)(Kbase + (size_t)((KERN_KBASE) + sr) * 1024 + sc);  \
    vreg = *(const uint4*)(Vbase + (size_t)sr * 4096 + (KERN_KBASE) + sc);    \
    *(uint4*)&Ks[0][sr][sc] = kreg;                                           \
    *(uint4*)&Vs[0][sr][sc] = vreg;                                           \
    if ((KERN_NC) > 1) {                                                      \
        kreg = *(const uint4*)(Kbase + (size_t)((KERN_KBASE) + 64 + sr) * 1024 + sc); \
        vreg = *(const uint4*)(Vbase + (size_t)sr * 4096 + (KERN_KBASE) + 64 + sc);   \
    }                                                                         \
    __syncthreads();                                                          \
    _Pragma("unroll 1")                                                       \
    for (int i = 0; i < (KERN_NC); ++i) {                                     \
        const int buf = i & 1;                                                \
        if (i + 1 < (KERN_NC)) {                                              \
            *(uint4*)&Ks[buf ^ 1][sr][sc] = kreg;                             \
            *(uint4*)&Vs[buf ^ 1][sr][sc] = vreg;                             \
        }                                                                     \
        if (i + 2 < (KERN_NC)) {                                              \
            const int kn = (KERN_KBASE) + (i + 2) * 64;                       \
            kreg = *(const uint4*)(Kbase + (size_t)(kn + sr) * 1024 + sc);    \
            vreg = *(const uint4*)(Vbase + (size_t)sr * 4096 + kn + sc);      \
        }                                                                     \
        const int k0 = (KERN_KBASE) + i * 64;                                 \
        if (k0 <= qw_ + 15) {                                                 \
            bhalf8 kf[4][2];                                                  \
            _Pragma("unroll")                                                 \
            for (int jn = 0; jn < 4; ++jn) {                                  \
                kf[jn][0] = *(const bhalf8*)&Ks[buf][jn * 16 + l16][quad * 8];\
                kf[jn][1] = *(const bhalf8*)&Ks[buf][jn * 16 + l16][32 + quad * 8]; \
            }                                                                 \
            floatx4 s_[4];                                                    \
            _Pragma("unroll")                                                 \
            for (int jn = 0; jn < 4; ++jn) {                                  \
                floatx4 z = {0.f, 0.f, 0.f, 0.f};                             \
                z = MFMA_BF16(kf[jn][0], qf0, z, 0, 0, 0);                    \
                z = MFMA_BF16(kf[jn][1], qf1, z, 0, 0, 0);                    \
                s_[jn] = z;                                                   \
            }                                                                 \
            const bool partial = (k0 + 64 > qw_);                             \
            float e[4][4];                                                    \
            _Pragma("unroll")                                                 \
            for (int jn = 0; jn < 4; ++jn)                                    \
                _Pragma("unroll")                                             \
                for (int g = 0; g < 4; ++g) {                                 \
                    float v = exp2f(s_[jn][g] * KS - CB);                     \
                    if (partial && (k0 + jn * 16 + quad * 4 + g > qrow)) v = 0.f; \
                    e[jn][g] = v;                                             \
                    lsum += v;                                                \
                }                                                             \
            uint4v w0 = {cvt_pk_bf16(e[0][0], e[0][1]), cvt_pk_bf16(e[0][2], e[0][3]), \
                         cvt_pk_bf16(e[1][0], e[1][1]), cvt_pk_bf16(e[1][2], e[1][3])}; \
            uint4v w1 = {cvt_pk_bf16(e[2][0], e[2][1]), cvt_pk_bf16(e[2][2], e[2][3]), \
                         cvt_pk_bf16(e[3][0], e[3][1]), cvt_pk_bf16(e[3][2], e[3][3])}; \
            bhalf8 af0 = __builtin_bit_cast(bhalf8, w0);                      \
            bhalf8 af1 = __builtin_bit_cast(bhalf8, w1);                      \
            _Pragma("unroll")                                                 \
            for (int nd = 0; nd < 4; ++nd) {                                  \
                const short* vrow = &Vs[buf][nd * 16 + l16][0];               \
                bhalf8 vf0, vf1;                                              \
                *(short4v*)&vf0       = *(const short4v*)(vrow + quad * 4);   \
                *((short4v*)&vf0 + 1) = *(const short4v*)(vrow + 16 + quad * 4); \
                *(short4v*)&vf1       = *(const short4v*)(vrow + 32 + quad * 4); \
                *((short4v*)&vf1 + 1) = *(const short4v*)(vrow + 48 + quad * 4); \
                o[nd] = MFMA_BF16(af0, vf0, o[nd], 0, 0, 0);                  \
                o[nd] = MFMA_BF16(af1, vf1, o[nd], 0, 0, 0);                  \
            }                                                                 \
        }                                                                     \
        __syncthreads();                                                      \
    }                                                                         \
    lsum += __shfl_xor(lsum, 16, 64);                                         \
    lsum += __shfl_xor(lsum, 32, 64);

#define ATTN_STORE_Y()                                                        \
    _Pragma("unroll")                                                         \
    for (int g = 0; g < 4; ++g) {                                             \
        const float r  = __shfl(lsum, quad * 4 + g, 64);                      \
        const float iv = 1.0f / r;                                            \
        const int qrow_o = qw_ + quad * 4 + g;                                \
        _Pragma("unroll")                                                     \
        for (int nd = 0; nd < 4; ++nd)                                        \
            Y[(size_t)(b * SEQ + qrow_o) * 1024 + h * 64 + nd * 16 + l16] =   \
                f2bf(o[nd][g] * iv);                                          \
    }

__global__ __launch_bounds__(512) void attn_v18(const short* __restrict__ Qo,
                                                const short* __restrict__ Ko,
                                                const short* __restrict__ Vt,
                                                short* __restrict__ Y,
                                                float* __restrict__ Pw,
                                                int* __restrict__ flags) {
    __shared__ __align__(16) short Ks[2][64][72];   // 18432 B, K chunk dbuf
    __shared__ __align__(16) short Vs[2][64][72];   // 18432 B, V^T chunk dbuf

    const int t    = threadIdx.x;
    const int wave = t >> 6, lane = t & 63, quad = lane >> 4, l16 = lane & 15;
    const int bid  = (int)blockIdx.x;
    const int bh   = bid & 31;                      // same for all 3 CU blocks
    const int g8   = (bid & 255) >> 5;              // 0..7
    const int grp  = bid >> 8;                      // 0,1,2
    int qt, nc, kbase, half;
    if (grp == 0)      { qt = 15 - g8; nc = 16 - g8; kbase = 0;               half = 0; }
    else if (grp == 1) { qt = 15 - g8; nc = 16 - g8; kbase = (16 - g8) * 64;  half = 1; }
    else               { qt = g8;      nc = 2 * (g8 + 1); kbase = 0;          half = -1; }
    const int b = bh >> 4, h = bh & 15;

    const short* Qbase = Qo + (size_t)b * SEQ * 1024 + h * 64;
    const short* Kbase = Ko + (size_t)b * SEQ * 1024 + h * 64;
    const short* Vbase = Vt + (size_t)h * 64 * 4096 + (size_t)b * SEQ;

    const int sr = t >> 3;            // staging row 0..63
    const int sc = (t & 7) * 8;       // staging col (elements)

    const float KS = 0.125f * 1.44269504f;   // score scale * log2(e)
    const float CB = 12.0f * 1.44269504f;    // fixed softmax offset

    const int qw_  = qt * 128 + wave * 16;   // wave's 16 q-rows
    const int qrow = qw_ + l16;              // this lane's softmax q-row
    const short* qr = Qbase + (size_t)qrow * 1024;
    bhalf8 qf0 = *(const bhalf8*)(qr + quad * 8);
    bhalf8 qf1 = *(const bhalf8*)(qr + 32 + quad * 8);

    float lsum = 0.f;
    floatx4 o[4];
#pragma unroll
    for (int nd = 0; nd < 4; ++nd) {
        floatx4 z = {0.f, 0.f, 0.f, 0.f};
        o[nd] = z;
    }

    ATTN_BODY(nc, kbase);

    if (half < 0) {                          // whole small tile: direct store
        ATTN_STORE_Y();
        return;
    }

    // ---- split-K combine (no spin): write own slab, fence, ticket ----
    const int tidx = bh * 8 + (qt - 8);                 // 0..255
    float* pb = Pw + (size_t)(tidx * 2 + half) * 8320;
#pragma unroll
    for (int g = 0; g < 4; ++g)
#pragma unroll
        for (int nd = 0; nd < 4; ++nd)
            pb[(wave * 16 + quad * 4 + g) * 64 + nd * 16 + l16] = o[nd][g];
    if (quad == 0) pb[8192 + wave * 16 + l16] = lsum;
    __threadfence();
    __syncthreads();
    int* tick = (int*)&Ks[0][0][0];          // LDS dead after loop
    if (t == 0) *tick = atomicAdd(&flags[tidx], 1);
    __syncthreads();
    if (*tick == 1) {                        // partner's slab is visible
        __threadfence();
        const float* qb = Pw + (size_t)(tidx * 2 + (1 - half)) * 8320;
#pragma unroll
        for (int g = 0; g < 4; ++g)
#pragma unroll
            for (int nd = 0; nd < 4; ++nd)
                o[nd][g] += qb[(wave * 16 + quad * 4 + g) * 64 + nd * 16 + l16];
        lsum += qb[8192 + wave * 16 + l16];
        ATTN_STORE_Y();
    }
}

// Fallback (ws too small): v17 — 2 blocks/CU, no workspace combine.
__global__ __launch_bounds__(512) void attn_v17f(const short* __restrict__ Qo,
                                                 const short* __restrict__ Ko,
                                                 const short* __restrict__ Vt,
                                                 short* __restrict__ Y) {
    __shared__ __align__(16) short Ks[2][64][72];
    __shared__ __align__(16) short Vs[2][64][72];
    const int t    = threadIdx.x;
    const int wave = t >> 6, lane = t & 63, quad = lane >> 4, l16 = lane & 15;
    const int bid  = (int)blockIdx.x;
    const int bh   = bid & 31;
    const int p    = (bid & 255) >> 5;
    const int qt   = (bid < 256) ? (15 - p) : p;
    const int b = bh >> 4, h = bh & 15;
    const int nc   = (qt + 1) * 2;
    const short* Qbase = Qo + (size_t)b * SEQ * 1024 + h * 64;
    const short* Kbase = Ko + (size_t)b * SEQ * 1024 + h * 64;
    const short* Vbase = Vt + (size_t)h * 64 * 4096 + (size_t)b * SEQ;
    const int sr = t >> 3, sc = (t & 7) * 8;
    const float KS = 0.125f * 1.44269504f;
    const float CB = 12.0f * 1.44269504f;
    const int qw_  = qt * 128 + wave * 16;
    const int qrow = qw_ + l16;
    const short* qr = Qbase + (size_t)qrow * 1024;
    bhalf8 qf0 = *(const bhalf8*)(qr + quad * 8);
    bhalf8 qf1 = *(const bhalf8*)(qr + 32 + quad * 8);
    float lsum = 0.f;
    floatx4 o[4];
#pragma unroll
    for (int nd = 0; nd < 4; ++nd) {
        floatx4 z = {0.f, 0.f, 0.f, 0.f};
        o[nd] = z;
    }
    ATTN_BODY(nc, 0);
    ATTN_STORE_Y();
}

// ---------------------------------------------------------------------------
extern "C" void kernel_launch(void* const* d_in, const int* in_sizes, int n_in,
                              void* d_out, int out_size, void* d_ws, size_t ws_size,
                              hipStream_t stream) {
    const float* x  = (const float*)d_in[0];
    const float* wq = (const float*)d_in[1];
    const float* wk = (const float*)d_in[2];
    const float* wv = (const float*)d_in[3];
    const float* wo = (const float*)d_in[4];

    short* xb   = (short*)d_ws;
    short* Qo   = xb + (size_t)4096 * 1024;
    short* Ko   = Qo + (size_t)4096 * 1024;
    short* Vt   = Ko + (size_t)4096 * 1024;
    short* wall = Vt + (size_t)1024 * 4096;
    short* wob  = wall + (size_t)3 * 1024 * 1024;
    float* Pw   = (float*)(wob + (size_t)1024 * 1024);
    int*   flags = (int*)((char*)Pw + (size_t)512 * 8320 * 4);
    const size_t needed = (size_t)(41943040) + (size_t)512 * 8320 * 4 + 1024;

    cast_all<<<dim3(4096), 256, 0, stream>>>(x, wq, wk, wv, wo, xb, wall);
    gemm_qkv2<<<dim3(16, 12), 512, 0, stream>>>(xb, wall, Qo, Ko, Vt);
    if (ws_size >= needed) {
        hipMemsetAsync(flags, 0, 256 * sizeof(int), stream);
        attn_v18<<<dim3(768), 512, 0, stream>>>(Qo, Ko, Vt, xb, Pw, flags);
    } else {
        attn_v17f<<<dim3(512), 512, 0, stream>>>(Qo, Ko, Vt, xb);
    }
    gemm_o2<<<dim3(32, 16), 256, 0, stream>>>(xb, wob, (float*)d_out);
}